// Round 6
// baseline (929.840 us; speedup 1.0000x reference)
//
#include <hip/hip_runtime.h>
#include <math.h>

#define N_TOK 8192
#define DIM 1024
#define FF 4096
#define NE 8
#define SLOT_CAP (N_TOK*2 + NE*256)   // 18432
#define MAXT256 72
#define MAXT128 136

typedef float f32x4 __attribute__((ext_vector_type(4)));
typedef _Float16 f16x8 __attribute__((ext_vector_type(8)));
typedef unsigned int u32x4 __attribute__((ext_vector_type(4)));

__device__ __forceinline__ unsigned short f2h(float f) {
    _Float16 h = (_Float16)f;
    return __builtin_bit_cast(unsigned short, h);
}

__device__ __forceinline__ void gl_lds16(const void* g, void* l) {
    __builtin_amdgcn_global_load_lds(
        (const __attribute__((address_space(1))) void*)g,
        (__attribute__((address_space(3))) void*)l, 16, 0, 0);
}

__device__ __forceinline__ void vw6() { asm volatile("s_waitcnt vmcnt(6)"   ::: "memory"); __builtin_amdgcn_sched_barrier(0); }
__device__ __forceinline__ void vw0() { asm volatile("s_waitcnt vmcnt(0)"   ::: "memory"); __builtin_amdgcn_sched_barrier(0); }
__device__ __forceinline__ void lw0() { asm volatile("s_waitcnt lgkmcnt(0)" ::: "memory"); __builtin_amdgcn_sched_barrier(0); }
#define BAR __builtin_amdgcn_s_barrier()

// ---------------- Router: fp32 logits, top-2, softmax, counts, x->fp16 ----------------
__global__ __launch_bounds__(256) void k_router(
    const float* __restrict__ x, const float* __restrict__ Wr,
    unsigned short* __restrict__ xh, int* __restrict__ ctl,
    int* __restrict__ tok2e, float* __restrict__ tok2w)
{
    __shared__ float wr[NE * DIM];
    const int t = threadIdx.x;
#pragma unroll
    for (int i = 0; i < (NE * DIM) / 256; ++i) wr[i * 256 + t] = Wr[i * 256 + t];
    __syncthreads();

    const int lane = t & 63;
    const int n = blockIdx.x * 4 + (t >> 6);
    const float* xr = x + (size_t)n * DIM;
    unsigned short* xhr = xh + (size_t)n * DIM;

    float acc[NE];
#pragma unroll
    for (int e = 0; e < NE; ++e) acc[e] = 0.f;
#pragma unroll
    for (int j = 0; j < DIM / 64; ++j) {
        int d = j * 64 + lane;
        float v = xr[d];
        xhr[d] = f2h(v);
#pragma unroll
        for (int e = 0; e < NE; ++e) acc[e] += v * wr[e * DIM + d];
    }
#pragma unroll
    for (int off = 32; off >= 1; off >>= 1) {
#pragma unroll
        for (int e = 0; e < NE; ++e) acc[e] += __shfl_xor(acc[e], off);
    }
    if (lane == 0) {
        int e0 = 0; float v0 = acc[0];
#pragma unroll
        for (int e = 1; e < NE; ++e) if (acc[e] > v0) { v0 = acc[e]; e0 = e; }
        int e1 = -1; float v1 = -1e30f;
#pragma unroll
        for (int e = 0; e < NE; ++e) if (e != e0 && acc[e] > v1) { v1 = acc[e]; e1 = e; }
        float tt = expf(v1 - v0);
        tok2e[2 * n] = e0; tok2e[2 * n + 1] = e1;
        tok2w[2 * n] = 1.f / (1.f + tt); tok2w[2 * n + 1] = tt / (1.f + tt);
        atomicAdd(&ctl[e0], 1);
        atomicAdd(&ctl[e1], 1);
    }
}

// ---------------- Setup: 256-padded offsets, both tile maps, parallel pad fill ----------------
__global__ __launch_bounds__(256) void k_setup(
    int* __restrict__ ctl, int* __restrict__ tos, float* __restrict__ gos)
{
    __shared__ int sh[NE * 2];
    const int t = threadIdx.x;
    if (t == 0) {
        int run = 0, T = 0, T128 = 0;
        for (int e = 0; e < NE; ++e) {
            ctl[16 + e] = run;
            int c = ctl[e];
            sh[e] = run; sh[NE + e] = c;
            int mt = (c + 255) >> 8;
            for (int j = 0; j < mt; ++j) { ctl[40 + T] = e; ctl[112 + T] = run + j * 256; ++T; }
            int mt128 = (c + 127) >> 7;
            for (int j = 0; j < mt128; ++j) { ctl[184 + T128] = e; ctl[320 + T128] = run + j * 128; ++T128; }
            run += mt * 256;
        }
        ctl[16 + NE] = run;
        ctl[32] = T; ctl[33] = T128;
    }
    __syncthreads();
    for (int e = 0; e < NE; ++e) {
        int off = sh[e], c = sh[NE + e];
        int pad = ((c + 255) >> 8) << 8;
        for (int s = c + t; s < pad; s += 256) { tos[off + s] = 0; gos[off + s] = 0.f; }
    }
}

// ---------------- Scatter ----------------
__global__ __launch_bounds__(256) void k_scatter(
    const int* __restrict__ tok2e, const float* __restrict__ tok2w,
    int* __restrict__ ctl, int* __restrict__ tos, float* __restrict__ gos)
{
    const int n = blockIdx.x * 256 + threadIdx.x;
#pragma unroll
    for (int k = 0; k < 2; ++k) {
        int e = tok2e[2 * n + k];
        int pos = atomicAdd(&ctl[8 + e], 1);
        int slot = ctl[16 + e] + pos;
        tos[slot] = n;
        gos[slot] = tok2w[2 * n + k];
    }
}

// ---------------- W convert: fp32 [E][KD][ND] -> fp16 [e][kt][khalf][n][32] (chunk-swizzled) ----------------
// element (k = kt*64 + h*32 + c*8 + j, n) stored at ((e*KT+kt)*2+h)*ND*32 + n*32 + ((c^(n&3))<<3) + j
__global__ __launch_bounds__(256) void k_wcvt(
    const float* __restrict__ W, unsigned short* __restrict__ Wt, int KD, int ND)
{
    __shared__ unsigned short Lt[64][72];
    const int t = threadIdx.x;
    const int e = blockIdx.z, kt = blockIdx.y, n0 = blockIdx.x * 64;
    const int KT = KD >> 6;
    const float* src = W + (size_t)e * KD * ND + (size_t)(kt * 64) * ND + n0;
#pragma unroll
    for (int i = 0; i < 4; ++i) {
        int kl = (t >> 4) + i * 16;
        f32x4 v = *reinterpret_cast<const f32x4*>(src + (size_t)kl * ND + (t & 15) * 4);
        int h = kl >> 5, c = (kl >> 3) & 3, j = kl & 7;
#pragma unroll
        for (int m = 0; m < 4; ++m) {
            int nl = (t & 15) * 4 + m;
            Lt[nl][h * 32 + ((c ^ (nl & 3)) << 3) + j] = f2h(v[m]);
        }
    }
    __syncthreads();
    const int nl = t >> 2, qq = t & 3;
#pragma unroll
    for (int h = 0; h < 2; ++h) {
        unsigned short* dst = Wt + ((size_t)(e * KT + kt) * 2 + h) * ((size_t)ND * 32)
                            + (size_t)(n0 + nl) * 32 + qq * 8;
        *reinterpret_cast<u32x4*>(dst) = *reinterpret_cast<const u32x4*>(&Lt[nl][h * 32 + qq * 8]);
    }
}

// ---------------- 256x256 8-phase pipelined grouped GEMM (8 waves, counted vmcnt) ----------------
// PHASE 1: gate*gelu(X@W1) -> H2 (tile-fmt). PHASE 2: H2@W2 -> atomicAdd(out).
template <int PHASE>
__global__ __launch_bounds__(512, 1) void k_g8(
    const unsigned short* __restrict__ Asrc, const unsigned short* __restrict__ Bh,
    unsigned short* __restrict__ Hout, float* __restrict__ Out,
    const int* __restrict__ ctl, const int* __restrict__ tos,
    const float* __restrict__ gos)
{
    constexpr int KD  = (PHASE == 1) ? DIM : FF;
    constexpr int ND  = (PHASE == 1) ? FF : DIM;
    constexpr int KT  = KD / 64;
    constexpr int NI  = KT / 2;
    constexpr int NXT = ND / 256;

    // bijective XCD-chunked remap (nwg divisible by 8 for both phases)
    const int nwg = gridDim.x * gridDim.y;
    const int lin = blockIdx.y * gridDim.x + blockIdx.x;
    const int q = nwg >> 3, r = nwg & 7;
    const int xcd = lin & 7;
    const int wg = (xcd < r ? xcd * (q + 1) : r * (q + 1) + (xcd - r) * q) + (lin >> 3);
    int yp, xp;
    if constexpr (PHASE == 1) { yp = wg / NXT;     xp = wg % NXT; }     // n-fastest: A in L2
    else                      { yp = wg % MAXT256; xp = wg / MAXT256; } // m-fastest: B in L2
    if (yp >= ctl[32]) return;
    const int e  = ctl[40 + yp];
    const int m0 = ctl[112 + yp];
    const int n0 = xp * 256;

    __shared__ __align__(1024) char lds[131072];   // 2 bufs x (A 32K + B 32K)

    const int t = threadIdx.x, l = t & 63, w = t >> 6;
    const int wm = w >> 2, wn = w & 3;             // 2M x 4N waves; wave tile 128x64
    const int fr = l & 15, hi = l >> 4;

    // ds_read bases (chunk swizzle: logical chunk hi stored at hi^(row&3))
    const int rA = (wm * 128 + fr) * 64 + ((hi ^ (fr & 3)) << 4);
    const int rB = 32768 + (wn * 64 + fr) * 64 + ((hi ^ (fr & 3)) << 4);

    // staging source pointers (2 gl_lds per half-tile per thread)
    const char* pa0; const char* pa1; const char* pb0; const char* pb1;
    if constexpr (PHASE == 1) {
        const int swz = ((l & 3) ^ ((l >> 2) & 3)) << 4;  // pre-swizzled global chunk
        pa0 = (const char*)Asrc + (size_t)tos[m0 + (w * 2 + 0) * 16 + (l >> 2)] * 2048 + swz;
        pa1 = (const char*)Asrc + (size_t)tos[m0 + (w * 2 + 1) * 16 + (l >> 2)] * 2048 + swz;
    } else {
        pa0 = (const char*)Asrc + (size_t)m0 * 64 + (w * 2) * 1024 + l * 16;
        pa1 = pa0 + 1024;
    }
    pb0 = (const char*)Bh + (size_t)e * KT * 2 * ((size_t)ND * 64)
        + (size_t)n0 * 64 + (w * 2) * 1024 + l * 16;
    pb1 = pb0 + 1024;

    auto STA = [&](int tt, int h, int buf) {
        char* d = lds + buf * 65536 + h * 16384 + w * 2048;
        int off;
        if constexpr (PHASE == 1) off = tt * 128 + h * 64;
        else                      off = (tt * 2 + h) * (SLOT_CAP * 64);
        gl_lds16(pa0 + off, d);
        gl_lds16(pa1 + off, d + 1024);
    };
    auto STB = [&](int tt, int h, int buf) {
        char* d = lds + buf * 65536 + 32768 + h * 16384 + w * 2048;
        const int off = (tt * 2 + h) * (ND * 64);
        gl_lds16(pb0 + off, d);
        gl_lds16(pb1 + off, d + 1024);
    };
    auto RDA = [&](f16x8 (&A)[4], int buf, int h, int qd) {
        const char* p = lds + buf * 65536 + h * 16384 + qd * 4096 + rA;
#pragma unroll
        for (int i = 0; i < 4; ++i) A[i] = *(const f16x8*)(p + i * 1024);
    };
    auto RDB = [&](f16x8 (&B)[4], int buf, int h) {
        const char* p = lds + buf * 65536 + h * 16384 + rB;
#pragma unroll
        for (int i = 0; i < 4; ++i) B[i] = *(const f16x8*)(p + i * 1024);
    };

    f16x8 afX[4], afY[4], bfX[4], bfY[4];
    f32x4 accL[4][4], accH[4][4];
#pragma unroll
    for (int a = 0; a < 4; ++a)
#pragma unroll
        for (int b = 0; b < 4; ++b) { accL[a][b] = f32x4{0.f,0.f,0.f,0.f}; accH[a][b] = f32x4{0.f,0.f,0.f,0.f}; }

    auto MM = [&](f16x8 (&A)[4], f16x8 (&B)[4], f32x4 (&C)[4][4]) {
        __builtin_amdgcn_s_setprio(1);
#pragma unroll
        for (int mi = 0; mi < 4; ++mi)
#pragma unroll
            for (int ni = 0; ni < 4; ++ni)
                C[mi][ni] = __builtin_amdgcn_mfma_f32_16x16x32_f16(A[mi], B[ni], C[mi][ni], 0, 0, 0);
        __builtin_amdgcn_s_setprio(0);
    };

    // prologue: tile0 (4 halves) + tile1 (3 halves) staged; vmcnt(6) => tile0 landed,
    // leftover in flight = {Bk0(1),Ak0(1),Bk1(1)} = exact steady state
    STB(0,0,0); STA(0,0,0); STB(0,1,0); STA(0,1,0);
    STB(1,0,1); STA(1,0,1); STB(1,1,1);
    vw6(); BAR;

    for (int it = 0; it < NI - 1; ++it) {
        const int tt = 2 * it;
        // p0: A q0 kh0 + B kh0 (buf0)            stage Ak1(t+1)->buf1
        RDA(afX,0,0,0); RDB(bfX,0,0); STA(tt+1,1,1); BAR; lw0(); MM(afX,bfX,accL); BAR;
        // p1: A q1 kh0                           stage Bk0(t+2)->buf0
        RDA(afY,0,0,1); STB(tt+2,0,0);               BAR; lw0(); MM(afY,bfX,accH); BAR;
        // p2: A q1 kh1 + B kh1                   stage Ak0(t+2)->buf0
        RDA(afY,0,1,1); RDB(bfY,0,1); STA(tt+2,0,0); BAR; lw0(); MM(afY,bfY,accH); BAR;
        // p3: A q0 kh1                           stage Bk1(t+2)->buf0   [vmcnt(6)]
        RDA(afX,0,1,0); STB(tt+2,1,0);               BAR; lw0(); MM(afX,bfY,accL); vw6(); BAR;
        // p4..p7: same on buf1 (tile t+1), staging t+2/t+3
        RDA(afX,1,0,0); RDB(bfX,1,0); STA(tt+2,1,0); BAR; lw0(); MM(afX,bfX,accL); BAR;
        RDA(afY,1,0,1); STB(tt+3,0,1);               BAR; lw0(); MM(afY,bfX,accH); BAR;
        RDA(afY,1,1,1); RDB(bfY,1,1); STA(tt+3,0,1); BAR; lw0(); MM(afY,bfY,accH); BAR;
        RDA(afX,1,1,0); STB(tt+3,1,1);               BAR; lw0(); MM(afX,bfY,accL); vw6(); BAR;
    }
    // final iteration (tiles KT-2, KT-1): only p0's A-k1 stage remains; drain at p3
    RDA(afX,0,0,0); RDB(bfX,0,0); STA(KT-1,1,1); BAR; lw0(); MM(afX,bfX,accL); BAR;
    RDA(afY,0,0,1);                              BAR; lw0(); MM(afY,bfX,accH); BAR;
    RDA(afY,0,1,1); RDB(bfY,0,1);                BAR; lw0(); MM(afY,bfY,accH); BAR;
    RDA(afX,0,1,0);                              BAR; lw0(); MM(afX,bfY,accL); vw0(); BAR;
    RDA(afX,1,0,0); RDB(bfX,1,0);                BAR; lw0(); MM(afX,bfX,accL); BAR;
    RDA(afY,1,0,1);                              BAR; lw0(); MM(afY,bfX,accH); BAR;
    RDA(afY,1,1,1); RDB(bfY,1,1);                BAR; lw0(); MM(afY,bfY,accH); BAR;
    RDA(afX,1,1,0);                              BAR; lw0(); MM(afX,bfY,accL);

    // epilogue
    auto EPI = [&](f32x4 (&C)[4][4], int rowoff) {
#pragma unroll
        for (int mi = 0; mi < 4; ++mi) {
#pragma unroll
            for (int rr = 0; rr < 4; ++rr) {
                const int srow = m0 + wm * 128 + rowoff + mi * 16 + hi * 4 + rr;
                if constexpr (PHASE == 1) {
                    const float gate = gos[srow];
#pragma unroll
                    for (int ni = 0; ni < 4; ++ni) {
                        int col = n0 + wn * 64 + ni * 16 + fr;
                        float v = C[mi][ni][rr];
                        float g = gate * 0.5f * v * (1.f + erff(v * 0.70710678118654752f));
                        int kt2 = col >> 6, h2 = (col >> 5) & 1, c2 = (col >> 3) & 3, j2 = col & 7;
                        Hout[((size_t)(kt2 * 2 + h2) * SLOT_CAP + srow) * 32 +
                             ((c2 ^ (srow & 3)) << 3) + j2] = f2h(g);
                    }
                } else {
                    int tok = tos[srow];
                    float* orow = Out + (size_t)tok * DIM + n0 + wn * 64 + fr;
#pragma unroll
                    for (int ni = 0; ni < 4; ++ni)
                        atomicAdd(&orow[ni * 16], C[mi][ni][rr]);
                }
            }
        }
    };
    EPI(accL, 0);
    EPI(accH, 64);
}

// ---------------- Fallback 128-tile GEMM (reg-staged fp32 B; used if ws too small) ----------------
template <int PHASE>
__global__ __launch_bounds__(256) void k_gemm_fb(
    const unsigned short* __restrict__ Asrc, const float* __restrict__ Bf,
    unsigned short* __restrict__ Hout, float* __restrict__ Out,
    const int* __restrict__ ctl, const int* __restrict__ tos,
    const float* __restrict__ gos)
{
    constexpr int KD = (PHASE == 1) ? DIM : FF;
    constexpr int ND = (PHASE == 1) ? FF : DIM;
    constexpr int KT = KD / 64;

    const int tidx = blockIdx.y;
    if (tidx >= ctl[33]) return;
    const int e  = ctl[184 + tidx];
    const int m0 = ctl[320 + tidx];
    const int n0 = blockIdx.x * 128;

    __shared__ __align__(16) unsigned short Al[128 * 64];
    __shared__ __align__(16) unsigned short Bl[128 * 64];
    char* Alc = (char*)Al;
    char* Blc = (char*)Bl;

    const int t = threadIdx.x, lane = t & 63, wv = t >> 6;
    const int wm = wv >> 1, wn = wv & 1;

    const unsigned short* asrc[4];
    if (PHASE == 1) {
        const int swz = ((lane & 7) ^ (lane >> 3)) * 8;
#pragma unroll
        for (int i = 0; i < 4; ++i) {
            int row = i * 32 + wv * 8 + (lane >> 3);
            asrc[i] = Asrc + (size_t)tos[m0 + row] * KD + swz;
        }
    }
    const int lin = wv * 512 + lane * 8;

    f32x4 acc[4][4];
#pragma unroll
    for (int a = 0; a < 4; ++a)
#pragma unroll
        for (int b = 0; b < 4; ++b) acc[a][b] = f32x4{0.f, 0.f, 0.f, 0.f};

    for (int kt = 0; kt < KT; ++kt) {
        if (PHASE == 1) {
#pragma unroll
            for (int i = 0; i < 4; ++i)
                gl_lds16(asrc[i] + kt * 64, Al + i * 2048 + wv * 512);
        } else {
            const unsigned short* ab = Asrc + ((size_t)kt * SLOT_CAP + m0) * 64;
#pragma unroll
            for (int i = 0; i < 4; ++i)
                gl_lds16(ab + i * 2048 + lin, Al + i * 2048 + wv * 512);
        }
        {
            const float* Wf = Bf + (size_t)e * KD * ND;
            const int kb = (wv >> 1) * 32 + (lane >> 4) * 8;
            const int n4 = (wv & 1) * 64 + (lane & 15) * 4;
            f32x4 rr[8];
#pragma unroll
            for (int r2 = 0; r2 < 8; ++r2)
                rr[r2] = *reinterpret_cast<const f32x4*>(
                    Wf + (size_t)(kt * 64 + kb + r2) * ND + n0 + n4);
#pragma unroll
            for (int m = 0; m < 4; ++m) {
                f16x8 v;
#pragma unroll
                for (int r2 = 0; r2 < 8; ++r2) v[r2] = (_Float16)rr[r2][m];
                int nn = n4 + m;
                *reinterpret_cast<f16x8*>(Blc + nn * 128 + (((kb >> 3) ^ (nn & 7)) << 4)) = v;
            }
        }
        __syncthreads();
#pragma unroll
        for (int kc = 0; kc < 2; ++kc) {
            const int cb = kc * 4 + (lane >> 4);
            f16x8 af[4], bf[4];
#pragma unroll
            for (int mi = 0; mi < 4; ++mi) {
                int row = wm * 64 + mi * 16 + (lane & 15);
                af[mi] = *reinterpret_cast<const f16x8*>(Alc + row * 128 + ((cb ^ (row & 7)) << 4));
            }
#pragma unroll
            for (int ni = 0; ni < 4; ++ni) {
                int col = wn * 64 + ni * 16 + (lane & 15);
                bf[ni] = *reinterpret_cast<const f16x8*>(Blc + col * 128 + ((cb ^ (col & 7)) << 4));
            }
#pragma unroll
            for (int mi = 0; mi < 4; ++mi)
#pragma unroll
                for (int ni = 0; ni < 4; ++ni)
                    acc[mi][ni] = __builtin_amdgcn_mfma_f32_16x16x32_f16(
                        af[mi], bf[ni], acc[mi][ni], 0, 0, 0);
        }
        __syncthreads();
    }

#pragma unroll
    for (int mi = 0; mi < 4; ++mi) {
#pragma unroll
        for (int rr = 0; rr < 4; ++rr) {
            const int srow = m0 + wm * 64 + mi * 16 + (lane >> 4) * 4 + rr;
            if (PHASE == 1) {
                const float gate = gos[srow];
#pragma unroll
                for (int ni = 0; ni < 4; ++ni) {
                    int col = n0 + wn * 64 + ni * 16 + (lane & 15);
                    float v = acc[mi][ni][rr];
                    float g = gate * 0.5f * v * (1.f + erff(v * 0.70710678118654752f));
                    int kl = col & 63;
                    Hout[((size_t)(col >> 6) * SLOT_CAP + srow) * 64 +
                         (((kl >> 3) ^ (srow & 7)) << 3) + (kl & 7)] = f2h(g);
                }
            } else {
                int tok = tos[srow];
                float* orow = Out + (size_t)tok * DIM + n0 + wn * 64 + (lane & 15);
#pragma unroll
                for (int ni = 0; ni < 4; ++ni)
                    atomicAdd(&orow[ni * 16], acc[mi][ni][rr]);
            }
        }
    }
}

// ---------------- launch ----------------
extern "C" void kernel_launch(void* const* d_in, const int* in_sizes, int n_in,
                              void* d_out, int out_size, void* d_ws, size_t ws_size,
                              hipStream_t stream) {
    (void)in_sizes; (void)n_in;
    const float* x  = (const float*)d_in[0];
    const float* Wr = (const float*)d_in[1];
    const float* W1 = (const float*)d_in[2];
    const float* W2 = (const float*)d_in[3];
    float* out = (float*)d_out;
    char* ws = (char*)d_ws;

    // ws layout (bytes):
    //   0          ctl (4 KB)
    //   4096       tok2e (64 KB)
    //   69632      tok2w (64 KB)
    //   135168     tos (18432*4)
    //   208896     gos (18432*4)
    //   282624     xh fp16 (16 MB)            -> 17,059,840
    //   17059840   H2 fp16 tile-fmt (151 MB)  -> 168,054,784
    //   168054784  Wt fp16 (64 MB, reused)    -> 235,163,648
    const size_t NEED_FB   = 168054784ULL;
    const size_t NEED_FULL = 235163648ULL;
    if (ws_size < NEED_FB) return;
    const bool big = ws_size >= NEED_FULL;

    int*            ctl = (int*)(ws + 0);
    int*            t2e = (int*)(ws + 4096);
    float*          t2w = (float*)(ws + 69632);
    int*            tos = (int*)(ws + 135168);
    float*          gos = (float*)(ws + 208896);
    unsigned short* xh  = (unsigned short*)(ws + 282624);
    unsigned short* H2  = (unsigned short*)(ws + 17059840);
    unsigned short* Wt  = (unsigned short*)(ws + 168054784);

    hipMemsetAsync(ctl, 0, 64, stream);
    hipMemsetAsync(d_out, 0, (size_t)out_size * 4, stream);

    k_router <<<dim3(N_TOK / 4), dim3(256), 0, stream>>>(x, Wr, xh, ctl, t2e, t2w);
    k_setup  <<<dim3(1), dim3(256), 0, stream>>>(ctl, tos, gos);
    k_scatter<<<dim3(N_TOK / 256), dim3(256), 0, stream>>>(t2e, t2w, ctl, tos, gos);

    if (big) {
        k_wcvt<<<dim3(64, 16, 8), dim3(256), 0, stream>>>(W1, Wt, DIM, FF);
        k_g8<1><<<dim3(FF / 256, MAXT256), dim3(512), 0, stream>>>(
            xh, Wt, H2, nullptr, ctl, tos, gos);
        k_wcvt<<<dim3(16, 64, 8), dim3(256), 0, stream>>>(W2, Wt, FF, DIM);
        k_g8<2><<<dim3(DIM / 256, MAXT256), dim3(512), 0, stream>>>(
            H2, Wt, nullptr, out, ctl, tos, gos);
    } else {
        k_gemm_fb<1><<<dim3(FF / 128, MAXT128), dim3(256), 0, stream>>>(
            xh, W1, H2, nullptr, ctl, tos, gos);
        k_gemm_fb<2><<<dim3(DIM / 128, MAXT128), dim3(256), 0, stream>>>(
            H2, W2, nullptr, out, ctl, tos, gos);
    }
}

// Round 7
// 696.000 us; speedup vs baseline: 1.3360x; 1.3360x over previous
//
#include <hip/hip_runtime.h>
#include <math.h>

#define N_TOK 8192
#define DIM 1024
#define FF 4096
#define NE 8
#define SLOT_CAP (N_TOK*2 + NE*256)   // 18432
#define MAXT256 72
#define MAXT128 136

typedef float f32x4 __attribute__((ext_vector_type(4)));
typedef _Float16 f16x8 __attribute__((ext_vector_type(8)));
typedef unsigned int u32x4 __attribute__((ext_vector_type(4)));

__device__ __forceinline__ unsigned short f2h(float f) {
    _Float16 h = (_Float16)f;
    return __builtin_bit_cast(unsigned short, h);
}

__device__ __forceinline__ void gl_lds16(const void* g, void* l) {
    __builtin_amdgcn_global_load_lds(
        (const __attribute__((address_space(1))) void*)g,
        (__attribute__((address_space(3))) void*)l, 16, 0, 0);
}

__device__ __forceinline__ void vw6() { asm volatile("s_waitcnt vmcnt(6)"   ::: "memory"); __builtin_amdgcn_sched_barrier(0); }
__device__ __forceinline__ void vw0() { asm volatile("s_waitcnt vmcnt(0)"   ::: "memory"); __builtin_amdgcn_sched_barrier(0); }
__device__ __forceinline__ void lw0() { asm volatile("s_waitcnt lgkmcnt(0)" ::: "memory"); __builtin_amdgcn_sched_barrier(0); }
#define BAR __builtin_amdgcn_s_barrier()

// ---------------- Router: fp32 logits, top-2, softmax weights, x->fp16 (no atomics) ----------------
__global__ __launch_bounds__(256) void k_router(
    const float* __restrict__ x, const float* __restrict__ Wr,
    unsigned short* __restrict__ xh,
    int* __restrict__ tok2e, float* __restrict__ tok2w)
{
    __shared__ float wr[NE * DIM];
    const int t = threadIdx.x;
#pragma unroll
    for (int i = 0; i < (NE * DIM) / 256; ++i) wr[i * 256 + t] = Wr[i * 256 + t];
    __syncthreads();

    const int lane = t & 63;
    const int n = blockIdx.x * 4 + (t >> 6);
    const float* xr = x + (size_t)n * DIM;
    unsigned short* xhr = xh + (size_t)n * DIM;

    float acc[NE];
#pragma unroll
    for (int e = 0; e < NE; ++e) acc[e] = 0.f;
#pragma unroll
    for (int j = 0; j < DIM / 64; ++j) {
        int d = j * 64 + lane;
        float v = xr[d];
        xhr[d] = f2h(v);
#pragma unroll
        for (int e = 0; e < NE; ++e) acc[e] += v * wr[e * DIM + d];
    }
#pragma unroll
    for (int off = 32; off >= 1; off >>= 1) {
#pragma unroll
        for (int e = 0; e < NE; ++e) acc[e] += __shfl_xor(acc[e], off);
    }
    if (lane == 0) {
        int e0 = 0; float v0 = acc[0];
#pragma unroll
        for (int e = 1; e < NE; ++e) if (acc[e] > v0) { v0 = acc[e]; e0 = e; }
        int e1 = -1; float v1 = -1e30f;
#pragma unroll
        for (int e = 0; e < NE; ++e) if (e != e0 && acc[e] > v1) { v1 = acc[e]; e1 = e; }
        float tt = expf(v1 - v0);
        tok2e[2 * n] = e0; tok2e[2 * n + 1] = e1;
        tok2w[2 * n] = 1.f / (1.f + tt); tok2w[2 * n + 1] = tt / (1.f + tt);
    }
}

// ---------------- Count: LDS histogram, 8 global atomics per block ----------------
__global__ __launch_bounds__(256) void k_count(
    const int* __restrict__ tok2e, int* __restrict__ ctl)
{
    __shared__ int h[NE];
    const int t = threadIdx.x;
    if (t < NE) h[t] = 0;
    __syncthreads();
    const int n = blockIdx.x * 256 + t;
    atomicAdd(&h[tok2e[2 * n]], 1);
    atomicAdd(&h[tok2e[2 * n + 1]], 1);
    __syncthreads();
    if (t < NE) atomicAdd(&ctl[t], h[t]);
}

// ---------------- Setup: 256-padded offsets, both tile maps, parallel pad fill ----------------
__global__ __launch_bounds__(256) void k_setup(
    int* __restrict__ ctl, int* __restrict__ tos, float* __restrict__ gos)
{
    __shared__ int sh[NE * 2];
    const int t = threadIdx.x;
    if (t == 0) {
        int run = 0, T = 0, T128 = 0;
        for (int e = 0; e < NE; ++e) {
            ctl[16 + e] = run;
            int c = ctl[e];
            sh[e] = run; sh[NE + e] = c;
            int mt = (c + 255) >> 8;
            for (int j = 0; j < mt; ++j) { ctl[40 + T] = e; ctl[112 + T] = run + j * 256; ++T; }
            int mt128 = (c + 127) >> 7;
            for (int j = 0; j < mt128; ++j) { ctl[184 + T128] = e; ctl[320 + T128] = run + j * 128; ++T128; }
            run += mt * 256;
        }
        ctl[16 + NE] = run;
        ctl[32] = T; ctl[33] = T128;
    }
    __syncthreads();
    for (int e = 0; e < NE; ++e) {
        int off = sh[e], c = sh[NE + e];
        int pad = ((c + 255) >> 8) << 8;
        for (int s = c + t; s < pad; s += 256) { tos[off + s] = 0; gos[off + s] = 0.f; }
    }
}

// ---------------- Scatter: LDS histogram + block-level cursor reservation ----------------
__global__ __launch_bounds__(256) void k_scatter(
    const int* __restrict__ tok2e, const float* __restrict__ tok2w,
    int* __restrict__ ctl, int* __restrict__ tos, float* __restrict__ gos)
{
    __shared__ int h[NE], base[NE];
    const int t = threadIdx.x;
    if (t < NE) h[t] = 0;
    __syncthreads();
    const int n = blockIdx.x * 256 + t;
    const int e0 = tok2e[2 * n], e1 = tok2e[2 * n + 1];
    const int p0 = atomicAdd(&h[e0], 1);
    const int p1 = atomicAdd(&h[e1], 1);
    __syncthreads();
    if (t < NE) base[t] = ctl[16 + t] + atomicAdd(&ctl[8 + t], h[t]);
    __syncthreads();
    const int s0 = base[e0] + p0, s1 = base[e1] + p1;
    tos[s0] = n; gos[s0] = tok2w[2 * n];
    tos[s1] = n; gos[s1] = tok2w[2 * n + 1];
}

// ---------------- W convert: fp32 [E][KD][ND] -> fp16 [e][kt][h][n][32] chunk-swizzled ----------------
// element (k = kt*64 + h*32 + c*8 + j, n) at ((e*KT+kt)*2+h)*ND*32 + n*32 + ((c ^ ((n>>1)&3))<<3) + j
__global__ __launch_bounds__(256) void k_wcvt(
    const float* __restrict__ W, unsigned short* __restrict__ Wt, int KD, int ND)
{
    __shared__ unsigned short Lt[64][72];
    const int t = threadIdx.x;
    const int e = blockIdx.z, kt = blockIdx.y, n0 = blockIdx.x * 64;
    const int KT = KD >> 6;
    const float* src = W + (size_t)e * KD * ND + (size_t)(kt * 64) * ND + n0;
#pragma unroll
    for (int i = 0; i < 4; ++i) {
        int kl = (t >> 4) + i * 16;
        f32x4 v = *reinterpret_cast<const f32x4*>(src + (size_t)kl * ND + (t & 15) * 4);
        int h = kl >> 5, c = (kl >> 3) & 3, j = kl & 7;
#pragma unroll
        for (int m = 0; m < 4; ++m) {
            int nl = (t & 15) * 4 + m;
            Lt[nl][h * 32 + ((c ^ ((nl >> 1) & 3)) << 3) + j] = f2h(v[m]);
        }
    }
    __syncthreads();
    const int nl = t >> 2, qq = t & 3;
#pragma unroll
    for (int h = 0; h < 2; ++h) {
        unsigned short* dst = Wt + ((size_t)(e * KT + kt) * 2 + h) * ((size_t)ND * 32)
                            + (size_t)(n0 + nl) * 32 + qq * 8;
        *reinterpret_cast<u32x4*>(dst) = *reinterpret_cast<const u32x4*>(&Lt[nl][h * 32 + qq * 8]);
    }
}

// ---------------- 256x256 8-phase pipelined grouped GEMM (8 waves, counted vmcnt) ----------------
// PHASE 1: gate*gelu(X@W1) -> H2 (tile-fmt). PHASE 2: H2@W2 -> atomicAdd(out), K-split.
template <int PHASE, int KSPLIT>
__global__ __launch_bounds__(512, 1) void k_g8(
    const unsigned short* __restrict__ Asrc, const unsigned short* __restrict__ Bh,
    unsigned short* __restrict__ Hout, float* __restrict__ Out,
    const int* __restrict__ ctl, const int* __restrict__ tos,
    const float* __restrict__ gos)
{
    constexpr int KD  = (PHASE == 1) ? DIM : FF;
    constexpr int ND  = (PHASE == 1) ? FF : DIM;
    constexpr int KT  = KD / 64;
    constexpr int KTL = KT / KSPLIT;
    constexpr int NI  = KTL / 2;
    constexpr int NXT = ND / 256;

    // bijective XCD-chunked remap (per z-plane; nwg divisible by 8)
    const int nwg = gridDim.x * gridDim.y;
    const int lin = blockIdx.y * gridDim.x + blockIdx.x;
    const int q = nwg >> 3, r = nwg & 7;
    const int xcd = lin & 7;
    const int wg = (xcd < r ? xcd * (q + 1) : r * (q + 1) + (xcd - r) * q) + (lin >> 3);
    int yp, xp;
    if constexpr (PHASE == 1) { yp = wg / NXT;     xp = wg % NXT; }     // n-fastest: A in L2
    else                      { yp = wg % MAXT256; xp = wg / MAXT256; } // m-fastest: B in L2
    if (yp >= ctl[32]) return;
    const int e  = ctl[40 + yp];
    const int m0 = ctl[112 + yp];
    const int n0 = xp * 256;
    const int kt0 = (KSPLIT > 1) ? (int)blockIdx.z * KTL : 0;

    __shared__ __align__(1024) char lds[131072];   // 2 bufs x (A 32K + B 32K)

    const int t = threadIdx.x, l = t & 63, w = t >> 6;
    const int wm = w >> 2, wn = w & 3;             // 2M x 4N waves; wave tile 128x64
    const int fr = l & 15, hi = l >> 4;

    // ds_read bases; swizzle key (row>>1)&3 -> 2-way (free) bank pattern
    const int rA = (wm * 128 + fr) * 64 + ((hi ^ ((fr >> 1) & 3)) << 4);
    const int rB = 32768 + (wn * 64 + fr) * 64 + ((hi ^ ((fr >> 1) & 3)) << 4);

    // staging source pointers (2 gl_lds per half-tile per thread; dest row = w*32+i*16+(l>>2))
    const char* pa0; const char* pa1; const char* pb0;
    if constexpr (PHASE == 1) {
        const int swz = ((l & 3) ^ ((l >> 3) & 3)) << 4;  // pre-swizzled global chunk
        pa0 = (const char*)Asrc + (size_t)tos[m0 + w * 32 + (l >> 2)]      * 2048 + swz;
        pa1 = (const char*)Asrc + (size_t)tos[m0 + w * 32 + 16 + (l >> 2)] * 2048 + swz;
    } else {
        pa0 = (const char*)Asrc + ((size_t)(kt0 * 2) * SLOT_CAP + m0) * 64 + w * 2048 + l * 16;
        pa1 = pa0 + 1024;
    }
    pb0 = (const char*)Bh + (size_t)(e * KT + kt0) * 2 * ((size_t)ND * 64)
        + (size_t)n0 * 64 + w * 2048 + l * 16;

    auto STA = [&](int tt, int h, int buf) {
        char* d = lds + buf * 65536 + h * 16384 + w * 2048;
        int off;
        if constexpr (PHASE == 1) off = (kt0 + tt) * 128 + h * 64;
        else                      off = (tt * 2 + h) * (SLOT_CAP * 64);
        gl_lds16(pa0 + off, d);
        gl_lds16(pa1 + off, d + 1024);
    };
    auto STB = [&](int tt, int h, int buf) {
        char* d = lds + buf * 65536 + 32768 + h * 16384 + w * 2048;
        const int off = (tt * 2 + h) * (ND * 64);
        gl_lds16(pb0 + off, d);
        gl_lds16(pb0 + off + 1024, d + 1024);
    };
    auto RDA = [&](f16x8 (&A)[4], int buf, int h, int qd) {
        const char* p = lds + buf * 65536 + h * 16384 + qd * 4096 + rA;
#pragma unroll
        for (int i = 0; i < 4; ++i) A[i] = *(const f16x8*)(p + i * 1024);
    };
    auto RDB = [&](f16x8 (&B)[4], int buf, int h) {
        const char* p = lds + buf * 65536 + h * 16384 + rB;
#pragma unroll
        for (int i = 0; i < 4; ++i) B[i] = *(const f16x8*)(p + i * 1024);
    };

    f16x8 afX[4], afY[4], bfX[4], bfY[4];
    f32x4 accL[4][4], accH[4][4];
#pragma unroll
    for (int a = 0; a < 4; ++a)
#pragma unroll
        for (int b = 0; b < 4; ++b) { accL[a][b] = f32x4{0.f,0.f,0.f,0.f}; accH[a][b] = f32x4{0.f,0.f,0.f,0.f}; }

    auto MM = [&](f16x8 (&A)[4], f16x8 (&B)[4], f32x4 (&C)[4][4]) {
        __builtin_amdgcn_s_setprio(1);
#pragma unroll
        for (int mi = 0; mi < 4; ++mi)
#pragma unroll
            for (int ni = 0; ni < 4; ++ni)
                C[mi][ni] = __builtin_amdgcn_mfma_f32_16x16x32_f16(A[mi], B[ni], C[mi][ni], 0, 0, 0);
        __builtin_amdgcn_s_setprio(0);
    };

    // prologue: tile0 fully + tile1 {B0,A0,B1}; vmcnt(6) => tile0 landed, carry = steady state
    STB(0,0,0); STA(0,0,0); STB(0,1,0); STA(0,1,0);
    STB(1,0,1); STA(1,0,1); STB(1,1,1);
    vw6(); BAR;

    for (int it = 0; it < NI - 1; ++it) {
        const int tt = 2 * it;
        RDA(afX,0,0,0); RDB(bfX,0,0); STA(tt+1,1,1); BAR; lw0(); MM(afX,bfX,accL); BAR;
        RDA(afY,0,0,1); STB(tt+2,0,0);               BAR; lw0(); MM(afY,bfX,accH); BAR;
        RDA(afY,0,1,1); RDB(bfY,0,1); STA(tt+2,0,0); BAR; lw0(); MM(afY,bfY,accH); BAR;
        RDA(afX,0,1,0); STB(tt+2,1,0);               BAR; lw0(); MM(afX,bfY,accL); vw6(); BAR;
        RDA(afX,1,0,0); RDB(bfX,1,0); STA(tt+2,1,0); BAR; lw0(); MM(afX,bfX,accL); BAR;
        RDA(afY,1,0,1); STB(tt+3,0,1);               BAR; lw0(); MM(afY,bfX,accH); BAR;
        RDA(afY,1,1,1); RDB(bfY,1,1); STA(tt+3,0,1); BAR; lw0(); MM(afY,bfY,accH); BAR;
        RDA(afX,1,1,0); STB(tt+3,1,1);               BAR; lw0(); MM(afX,bfY,accL); vw6(); BAR;
    }
    // final iteration (tiles KTL-2, KTL-1): only p0's stage remains; drain at p3
    RDA(afX,0,0,0); RDB(bfX,0,0); STA(KTL-1,1,1); BAR; lw0(); MM(afX,bfX,accL); BAR;
    RDA(afY,0,0,1);                               BAR; lw0(); MM(afY,bfX,accH); BAR;
    RDA(afY,0,1,1); RDB(bfY,0,1);                 BAR; lw0(); MM(afY,bfY,accH); BAR;
    RDA(afX,0,1,0);                               BAR; lw0(); MM(afX,bfY,accL); vw0(); BAR;
    RDA(afX,1,0,0); RDB(bfX,1,0);                 BAR; lw0(); MM(afX,bfX,accL); BAR;
    RDA(afY,1,0,1);                               BAR; lw0(); MM(afY,bfX,accH); BAR;
    RDA(afY,1,1,1); RDB(bfY,1,1);                 BAR; lw0(); MM(afY,bfY,accH); BAR;
    RDA(afX,1,1,0);                               BAR; lw0(); MM(afX,bfY,accL);

    // epilogue
    auto EPI = [&](f32x4 (&C)[4][4], int rowoff) {
#pragma unroll
        for (int mi = 0; mi < 4; ++mi) {
#pragma unroll
            for (int rr = 0; rr < 4; ++rr) {
                const int srow = m0 + wm * 128 + rowoff + mi * 16 + hi * 4 + rr;
                if constexpr (PHASE == 1) {
                    const float gate = gos[srow];
#pragma unroll
                    for (int ni = 0; ni < 4; ++ni) {
                        int col = n0 + wn * 64 + ni * 16 + fr;
                        float v = C[mi][ni][rr];
                        float g = gate * 0.5f * v * (1.f + erff(v * 0.70710678118654752f));
                        int kt2 = col >> 6, h2 = (col >> 5) & 1, c2 = (col >> 3) & 3, j2 = col & 7;
                        Hout[((size_t)(kt2 * 2 + h2) * SLOT_CAP + srow) * 32 +
                             ((c2 ^ ((srow >> 1) & 3)) << 3) + j2] = f2h(g);
                    }
                } else {
                    int tok = tos[srow];
                    float* orow = Out + (size_t)tok * DIM + n0 + wn * 64 + fr;
#pragma unroll
                    for (int ni = 0; ni < 4; ++ni)
                        atomicAdd(&orow[ni * 16], C[mi][ni][rr]);
                }
            }
        }
    };
    EPI(accL, 0);
    EPI(accH, 64);
}

// ---------------- Fallback 128-tile GEMM (reg-staged fp32 B; used if ws too small) ----------------
template <int PHASE>
__global__ __launch_bounds__(256) void k_gemm_fb(
    const unsigned short* __restrict__ Asrc, const float* __restrict__ Bf,
    unsigned short* __restrict__ Hout, float* __restrict__ Out,
    const int* __restrict__ ctl, const int* __restrict__ tos,
    const float* __restrict__ gos)
{
    constexpr int KD = (PHASE == 1) ? DIM : FF;
    constexpr int ND = (PHASE == 1) ? FF : DIM;
    constexpr int KT = KD / 64;

    const int tidx = blockIdx.y;
    if (tidx >= ctl[33]) return;
    const int e  = ctl[184 + tidx];
    const int m0 = ctl[320 + tidx];
    const int n0 = blockIdx.x * 128;

    __shared__ __align__(16) unsigned short Al[128 * 64];
    __shared__ __align__(16) unsigned short Bl[128 * 64];
    char* Alc = (char*)Al;
    char* Blc = (char*)Bl;

    const int t = threadIdx.x, lane = t & 63, wv = t >> 6;
    const int wm = wv >> 1, wn = wv & 1;

    const unsigned short* asrc[4];
    if (PHASE == 1) {
        const int swz = ((lane & 7) ^ (lane >> 3)) * 8;
#pragma unroll
        for (int i = 0; i < 4; ++i) {
            int row = i * 32 + wv * 8 + (lane >> 3);
            asrc[i] = Asrc + (size_t)tos[m0 + row] * KD + swz;
        }
    }
    const int lin = wv * 512 + lane * 8;

    f32x4 acc[4][4];
#pragma unroll
    for (int a = 0; a < 4; ++a)
#pragma unroll
        for (int b = 0; b < 4; ++b) acc[a][b] = f32x4{0.f, 0.f, 0.f, 0.f};

    for (int kt = 0; kt < KT; ++kt) {
        if (PHASE == 1) {
#pragma unroll
            for (int i = 0; i < 4; ++i)
                gl_lds16(asrc[i] + kt * 64, Al + i * 2048 + wv * 512);
        } else {
            const unsigned short* ab = Asrc + ((size_t)kt * SLOT_CAP + m0) * 64;
#pragma unroll
            for (int i = 0; i < 4; ++i)
                gl_lds16(ab + i * 2048 + lin, Al + i * 2048 + wv * 512);
        }
        {
            const float* Wf = Bf + (size_t)e * KD * ND;
            const int kb = (wv >> 1) * 32 + (lane >> 4) * 8;
            const int n4 = (wv & 1) * 64 + (lane & 15) * 4;
            f32x4 rr[8];
#pragma unroll
            for (int r2 = 0; r2 < 8; ++r2)
                rr[r2] = *reinterpret_cast<const f32x4*>(
                    Wf + (size_t)(kt * 64 + kb + r2) * ND + n0 + n4);
#pragma unroll
            for (int m = 0; m < 4; ++m) {
                f16x8 v;
#pragma unroll
                for (int r2 = 0; r2 < 8; ++r2) v[r2] = (_Float16)rr[r2][m];
                int nn = n4 + m;
                *reinterpret_cast<f16x8*>(Blc + nn * 128 + (((kb >> 3) ^ (nn & 7)) << 4)) = v;
            }
        }
        __syncthreads();
#pragma unroll
        for (int kc = 0; kc < 2; ++kc) {
            const int cb = kc * 4 + (lane >> 4);
            f16x8 af[4], bf[4];
#pragma unroll
            for (int mi = 0; mi < 4; ++mi) {
                int row = wm * 64 + mi * 16 + (lane & 15);
                af[mi] = *reinterpret_cast<const f16x8*>(Alc + row * 128 + ((cb ^ (row & 7)) << 4));
            }
#pragma unroll
            for (int ni = 0; ni < 4; ++ni) {
                int col = wn * 64 + ni * 16 + (lane & 15);
                bf[ni] = *reinterpret_cast<const f16x8*>(Blc + col * 128 + ((cb ^ (col & 7)) << 4));
            }
#pragma unroll
            for (int mi = 0; mi < 4; ++mi)
#pragma unroll
                for (int ni = 0; ni < 4; ++ni)
                    acc[mi][ni] = __builtin_amdgcn_mfma_f32_16x16x32_f16(
                        af[mi], bf[ni], acc[mi][ni], 0, 0, 0);
        }
        __syncthreads();
    }

#pragma unroll
    for (int mi = 0; mi < 4; ++mi) {
#pragma unroll
        for (int rr = 0; rr < 4; ++rr) {
            const int srow = m0 + wm * 64 + mi * 16 + (lane >> 4) * 4 + rr;
            if (PHASE == 1) {
                const float gate = gos[srow];
#pragma unroll
                for (int ni = 0; ni < 4; ++ni) {
                    int col = n0 + wn * 64 + ni * 16 + (lane & 15);
                    float v = acc[mi][ni][rr];
                    float g = gate * 0.5f * v * (1.f + erff(v * 0.70710678118654752f));
                    int kl = col & 63;
                    Hout[((size_t)(col >> 6) * SLOT_CAP + srow) * 64 +
                         (((kl >> 3) ^ (srow & 7)) << 3) + (kl & 7)] = f2h(g);
                }
            } else {
                int tok = tos[srow];
                float* orow = Out + (size_t)tok * DIM + n0 + wn * 64 + (lane & 15);
#pragma unroll
                for (int ni = 0; ni < 4; ++ni)
                    atomicAdd(&orow[ni * 16], acc[mi][ni][rr]);
            }
        }
    }
}

// ---------------- launch ----------------
extern "C" void kernel_launch(void* const* d_in, const int* in_sizes, int n_in,
                              void* d_out, int out_size, void* d_ws, size_t ws_size,
                              hipStream_t stream) {
    (void)in_sizes; (void)n_in;
    const float* x  = (const float*)d_in[0];
    const float* Wr = (const float*)d_in[1];
    const float* W1 = (const float*)d_in[2];
    const float* W2 = (const float*)d_in[3];
    float* out = (float*)d_out;
    char* ws = (char*)d_ws;

    // ws layout (bytes):
    //   0          ctl (4 KB)
    //   4096       tok2e (64 KB)
    //   69632      tok2w (64 KB)
    //   135168     tos (18432*4)
    //   208896     gos (18432*4)
    //   282624     xh fp16 (16 MB)            -> 17,059,840
    //   17059840   H2 fp16 tile-fmt (151 MB)  -> 168,054,784
    //   168054784  Wt fp16 (64 MB, reused)    -> 235,163,648
    const size_t NEED_FB   = 168054784ULL;
    const size_t NEED_FULL = 235163648ULL;
    if (ws_size < NEED_FB) return;
    const bool big = ws_size >= NEED_FULL;

    int*            ctl = (int*)(ws + 0);
    int*            t2e = (int*)(ws + 4096);
    float*          t2w = (float*)(ws + 69632);
    int*            tos = (int*)(ws + 135168);
    float*          gos = (float*)(ws + 208896);
    unsigned short* xh  = (unsigned short*)(ws + 282624);
    unsigned short* H2  = (unsigned short*)(ws + 17059840);
    unsigned short* Wt  = (unsigned short*)(ws + 168054784);

    hipMemsetAsync(ctl, 0, 64, stream);
    hipMemsetAsync(d_out, 0, (size_t)out_size * 4, stream);

    k_router <<<dim3(N_TOK / 4), dim3(256), 0, stream>>>(x, Wr, xh, t2e, t2w);
    k_count  <<<dim3(N_TOK / 256), dim3(256), 0, stream>>>(t2e, ctl);
    k_setup  <<<dim3(1), dim3(256), 0, stream>>>(ctl, tos, gos);
    k_scatter<<<dim3(N_TOK / 256), dim3(256), 0, stream>>>(t2e, t2w, ctl, tos, gos);

    if (big) {
        k_wcvt<<<dim3(64, 16, 8), dim3(256), 0, stream>>>(W1, Wt, DIM, FF);
        k_g8<1, 1><<<dim3(FF / 256, MAXT256, 1), dim3(512), 0, stream>>>(
            xh, Wt, H2, nullptr, ctl, tos, gos);
        k_wcvt<<<dim3(16, 64, 8), dim3(256), 0, stream>>>(W2, Wt, FF, DIM);
        k_g8<2, 2><<<dim3(DIM / 256, MAXT256, 2), dim3(512), 0, stream>>>(
            H2, Wt, nullptr, out, ctl, tos, gos);
    } else {
        k_gemm_fb<1><<<dim3(FF / 128, MAXT128), dim3(256), 0, stream>>>(
            xh, W1, H2, nullptr, ctl, tos, gos);
        k_gemm_fb<2><<<dim3(DIM / 128, MAXT128), dim3(256), 0, stream>>>(
            H2, W2, nullptr, out, ctl, tos, gos);
    }
}

// Round 8
// 537.787 us; speedup vs baseline: 1.7290x; 1.2942x over previous
//
#include <hip/hip_runtime.h>
#include <math.h>

#define N_TOK 8192
#define DIM 1024
#define FF 4096
#define NE 8
#define SLOT_CAP (N_TOK*2 + NE*256)   // 18432
#define MAXT128 136

typedef float f32x4 __attribute__((ext_vector_type(4)));
typedef _Float16 f16x8 __attribute__((ext_vector_type(8)));
typedef unsigned int u32x4 __attribute__((ext_vector_type(4)));

__device__ __forceinline__ unsigned short f2h(float f) {
    _Float16 h = (_Float16)f;
    return __builtin_bit_cast(unsigned short, h);
}

__device__ __forceinline__ void gl_lds16(const void* g, void* l) {
    __builtin_amdgcn_global_load_lds(
        (const __attribute__((address_space(1))) void*)g,
        (__attribute__((address_space(3))) void*)l, 16, 0, 0);
}

__device__ __forceinline__ void vw4() { asm volatile("s_waitcnt vmcnt(4)"   ::: "memory"); __builtin_amdgcn_sched_barrier(0); }
__device__ __forceinline__ void vw0() { asm volatile("s_waitcnt vmcnt(0)"   ::: "memory"); __builtin_amdgcn_sched_barrier(0); }
__device__ __forceinline__ void lw0() { asm volatile("s_waitcnt lgkmcnt(0)" ::: "memory"); __builtin_amdgcn_sched_barrier(0); }
#define BAR __builtin_amdgcn_s_barrier()

// ---------------- Router: fp32 logits, top-2, softmax weights, x->fp16 (no atomics) ----------------
__global__ __launch_bounds__(256) void k_router(
    const float* __restrict__ x, const float* __restrict__ Wr,
    unsigned short* __restrict__ xh,
    int* __restrict__ tok2e, float* __restrict__ tok2w)
{
    __shared__ float wr[NE * DIM];
    const int t = threadIdx.x;
#pragma unroll
    for (int i = 0; i < (NE * DIM) / 256; ++i) wr[i * 256 + t] = Wr[i * 256 + t];
    __syncthreads();

    const int lane = t & 63;
    const int n = blockIdx.x * 4 + (t >> 6);
    const float* xr = x + (size_t)n * DIM;
    unsigned short* xhr = xh + (size_t)n * DIM;

    float acc[NE];
#pragma unroll
    for (int e = 0; e < NE; ++e) acc[e] = 0.f;
#pragma unroll
    for (int j = 0; j < DIM / 64; ++j) {
        int d = j * 64 + lane;
        float v = xr[d];
        xhr[d] = f2h(v);
#pragma unroll
        for (int e = 0; e < NE; ++e) acc[e] += v * wr[e * DIM + d];
    }
#pragma unroll
    for (int off = 32; off >= 1; off >>= 1) {
#pragma unroll
        for (int e = 0; e < NE; ++e) acc[e] += __shfl_xor(acc[e], off);
    }
    if (lane == 0) {
        int e0 = 0; float v0 = acc[0];
#pragma unroll
        for (int e = 1; e < NE; ++e) if (acc[e] > v0) { v0 = acc[e]; e0 = e; }
        int e1 = -1; float v1 = -1e30f;
#pragma unroll
        for (int e = 0; e < NE; ++e) if (e != e0 && acc[e] > v1) { v1 = acc[e]; e1 = e; }
        float tt = expf(v1 - v0);
        tok2e[2 * n] = e0; tok2e[2 * n + 1] = e1;
        tok2w[2 * n] = 1.f / (1.f + tt); tok2w[2 * n + 1] = tt / (1.f + tt);
    }
}

// ---------------- Count: LDS histogram, 8 global atomics per block ----------------
__global__ __launch_bounds__(256) void k_count(
    const int* __restrict__ tok2e, int* __restrict__ ctl)
{
    __shared__ int h[NE];
    const int t = threadIdx.x;
    if (t < NE) h[t] = 0;
    __syncthreads();
    const int n = blockIdx.x * 256 + t;
    atomicAdd(&h[tok2e[2 * n]], 1);
    atomicAdd(&h[tok2e[2 * n + 1]], 1);
    __syncthreads();
    if (t < NE) atomicAdd(&ctl[t], h[t]);
}

// ---------------- Setup: 256-padded offsets, both tile maps, parallel pad fill ----------------
__global__ __launch_bounds__(256) void k_setup(
    int* __restrict__ ctl, int* __restrict__ tos, float* __restrict__ gos)
{
    __shared__ int sh[NE * 2];
    const int t = threadIdx.x;
    if (t == 0) {
        int run = 0, T = 0, T128 = 0;
        for (int e = 0; e < NE; ++e) {
            ctl[16 + e] = run;
            int c = ctl[e];
            sh[e] = run; sh[NE + e] = c;
            int mt = (c + 255) >> 8;
            for (int j = 0; j < mt; ++j) { ctl[40 + T] = e; ctl[112 + T] = run + j * 256; ++T; }
            int mt128 = (c + 127) >> 7;
            for (int j = 0; j < mt128; ++j) { ctl[184 + T128] = e; ctl[320 + T128] = run + j * 128; ++T128; }
            run += mt * 256;
        }
        ctl[16 + NE] = run;
        ctl[32] = T; ctl[33] = T128;
    }
    __syncthreads();
    for (int e = 0; e < NE; ++e) {
        int off = sh[e], c = sh[NE + e];
        int pad = ((c + 255) >> 8) << 8;
        for (int s = c + t; s < pad; s += 256) { tos[off + s] = 0; gos[off + s] = 0.f; }
    }
}

// ---------------- Scatter: LDS histogram + block-level cursor reservation ----------------
__global__ __launch_bounds__(256) void k_scatter(
    const int* __restrict__ tok2e, const float* __restrict__ tok2w,
    int* __restrict__ ctl, int* __restrict__ tos, float* __restrict__ gos)
{
    __shared__ int h[NE], base[NE];
    const int t = threadIdx.x;
    if (t < NE) h[t] = 0;
    __syncthreads();
    const int n = blockIdx.x * 256 + t;
    const int e0 = tok2e[2 * n], e1 = tok2e[2 * n + 1];
    const int p0 = atomicAdd(&h[e0], 1);
    const int p1 = atomicAdd(&h[e1], 1);
    __syncthreads();
    if (t < NE) base[t] = ctl[16 + t] + atomicAdd(&ctl[8 + t], h[t]);
    __syncthreads();
    const int s0 = base[e0] + p0, s1 = base[e1] + p1;
    tos[s0] = n; gos[s0] = tok2w[2 * n];
    tos[s1] = n; gos[s1] = tok2w[2 * n + 1];
}

// ---------------- W convert: fp32 [E][KD][ND] -> fp16 planes [e][ktt(32k)][n][32] chunk-swizzled ----------------
// element (k = ktt*32 + c*8 + j, n) at byte (e*KD/64*2 + ktt)*ND*64 + n*64 + ((c ^ ((n>>1)&3))<<4) + j*2
__global__ __launch_bounds__(256) void k_wcvt(
    const float* __restrict__ W, unsigned short* __restrict__ Wt, int KD, int ND)
{
    __shared__ unsigned short Lt[64][72];
    const int t = threadIdx.x;
    const int e = blockIdx.z, kt = blockIdx.y, n0 = blockIdx.x * 64;
    const int KT = KD >> 6;
    const float* src = W + (size_t)e * KD * ND + (size_t)(kt * 64) * ND + n0;
#pragma unroll
    for (int i = 0; i < 4; ++i) {
        int kl = (t >> 4) + i * 16;
        f32x4 v = *reinterpret_cast<const f32x4*>(src + (size_t)kl * ND + (t & 15) * 4);
        int h = kl >> 5, c = (kl >> 3) & 3, j = kl & 7;
#pragma unroll
        for (int m = 0; m < 4; ++m) {
            int nl = (t & 15) * 4 + m;
            Lt[nl][h * 32 + ((c ^ ((nl >> 1) & 3)) << 3) + j] = f2h(v[m]);
        }
    }
    __syncthreads();
    const int nl = t >> 2, qq = t & 3;
#pragma unroll
    for (int h = 0; h < 2; ++h) {
        unsigned short* dst = Wt + ((size_t)(e * KT + kt) * 2 + h) * ((size_t)ND * 32)
                            + (size_t)(n0 + nl) * 32 + qq * 8;
        *reinterpret_cast<u32x4*>(dst) = *reinterpret_cast<const u32x4*>(&Lt[nl][h * 32 + qq * 8]);
    }
}

// ---------------- 128x128 BK=32 pipelined grouped GEMM (4 waves, 4-5 blocks/CU) ----------------
// PHASE 1: gate*gelu(X@W1) -> H2 (plane-fmt). PHASE 2: H2@W2 -> atomicAdd(out).
template <int PHASE>
__global__ __launch_bounds__(256) void k_gp32(
    const unsigned short* __restrict__ Asrc, const unsigned short* __restrict__ Bh,
    unsigned short* __restrict__ Hout, float* __restrict__ Out,
    const int* __restrict__ ctl, const int* __restrict__ tos,
    const float* __restrict__ gos)
{
    constexpr int KD = (PHASE == 1) ? DIM : FF;
    constexpr int ND = (PHASE == 1) ? FF : DIM;
    constexpr int KT = KD / 32;
    constexpr int NX = ND / 128;

    // bijective XCD remap: each XCD sweeps N-tiles of its M-tiles
    const int lin = blockIdx.y * NX + blockIdx.x;
    const int xcd = lin & 7, chunk = lin >> 3;
    const int xp = chunk & (NX - 1);
    const int yp = (chunk / NX) * 8 + xcd;
    if (yp >= ctl[33]) return;
    const int e  = ctl[184 + yp];
    const int m0 = ctl[320 + yp];
    const int n0 = xp * 128;

    __shared__ __align__(1024) char lds[2 * 16384];   // 2 bufs x (A 8K + B 8K)

    const int t = threadIdx.x, l = t & 63, w = t >> 6;
    const int wm = w >> 1, wn = w & 1;                 // 2x2 waves, 64x64 per wave
    const int fr = l & 15, hi = l >> 4;

    // staging sources (dest row = w*32 + i*16 + (l>>2), chunk = l&3)
    const char* pa0; const char* pa1; const char* pb;
    if constexpr (PHASE == 1) {
        const int swz = ((l & 3) ^ ((l >> 3) & 3)) << 4;   // pre-swizzled source chunk
        pa0 = (const char*)Asrc + (size_t)tos[m0 + w * 32 + (l >> 2)]      * 2048 + swz;
        pa1 = (const char*)Asrc + (size_t)tos[m0 + w * 32 + 16 + (l >> 2)] * 2048 + swz;
    } else {
        pa0 = (const char*)Asrc + (size_t)m0 * 64 + w * 2048 + l * 16;   // H2 pre-swizzled
        pa1 = nullptr;
    }
    pb = (const char*)Bh + (size_t)e * KD * ND * 2 + (size_t)n0 * 64 + w * 2048 + l * 16;

    auto STAGE = [&](int ktt, int buf) {
        char* da = lds + buf * 16384 + w * 2048;
        char* db = lds + buf * 16384 + 8192 + w * 2048;
        if constexpr (PHASE == 1) {
            gl_lds16(pa0 + ktt * 64, da);
            gl_lds16(pa1 + ktt * 64, da + 1024);
        } else {
            const char* s = pa0 + (size_t)ktt * (SLOT_CAP * 64);
            gl_lds16(s, da);
            gl_lds16(s + 1024, da + 1024);
        }
        const char* sb = pb + (size_t)ktt * (ND * 64);
        gl_lds16(sb, db);
        gl_lds16(sb + 1024, db + 1024);
    };

    // ds_read bases; swizzle key (row>>1)&3 at 16B granularity (measured conflict-free)
    const int key = (fr >> 1) & 3;
    const int A0 = (wm * 64 + fr) * 64 + ((hi ^ key) << 4);
    const int B0 = 8192 + (wn * 64 + fr) * 64 + ((hi ^ key) << 4);

    f16x8 af[4], bf[4];
    f32x4 acc[4][4];
#pragma unroll
    for (int a = 0; a < 4; ++a)
#pragma unroll
        for (int b = 0; b < 4; ++b) acc[a][b] = f32x4{0.f, 0.f, 0.f, 0.f};

    auto LDFRAG = [&](int buf) {
        const char* ba = lds + buf * 16384 + A0;
        const char* bb = lds + buf * 16384 + B0;
#pragma unroll
        for (int i = 0; i < 4; ++i) af[i] = *(const f16x8*)(ba + i * 1024);
#pragma unroll
        for (int i = 0; i < 4; ++i) bf[i] = *(const f16x8*)(bb + i * 1024);
    };
    auto MM = [&]() {
        __builtin_amdgcn_s_setprio(1);
#pragma unroll
        for (int mi = 0; mi < 4; ++mi)
#pragma unroll
            for (int ni = 0; ni < 4; ++ni)
                acc[mi][ni] = __builtin_amdgcn_mfma_f32_16x16x32_f16(
                    af[mi], bf[ni], acc[mi][ni], 0, 0, 0);
        __builtin_amdgcn_s_setprio(0);
    };

    // prologue: stage tiles 0,1; vw4 => tile0 landed, tile1 in flight (= steady state)
    STAGE(0, 0); STAGE(1, 1);
    vw4(); BAR;
    int cur = 0;

    for (int kt = 0; kt < KT - 2; ++kt) {
        LDFRAG(cur);                        // 8 ds_read_b128 from buf cur
        lw0();                              // own reads done
        BAR;                                // all waves done reading buf cur
        STAGE(kt + 2, cur);                 // tile kt+2 -> buf cur (4 loads in flight)
        MM();                               // 16 MFMA while loads fly
        vw4();                              // tile kt+1 landed (kt+2 still in flight)
        BAR;
        cur ^= 1;
    }
    // tile KT-2 (no further staging)
    LDFRAG(cur); lw0(); MM();
    vw0(); BAR;                             // tile KT-1 fully landed
    cur ^= 1;
    // tile KT-1
    LDFRAG(cur); lw0(); MM();

    // epilogue
#pragma unroll
    for (int mi = 0; mi < 4; ++mi) {
#pragma unroll
        for (int rr = 0; rr < 4; ++rr) {
            const int srow = m0 + wm * 64 + mi * 16 + hi * 4 + rr;
            if constexpr (PHASE == 1) {
                const float gate = gos[srow];
#pragma unroll
                for (int ni = 0; ni < 4; ++ni) {
                    int col = n0 + wn * 64 + ni * 16 + fr;
                    float v = acc[mi][ni][rr];
                    float g = gate * 0.5f * v * (1.f + erff(v * 0.70710678118654752f));
                    int p = col >> 5, c2 = (col >> 3) & 3, j2 = col & 7;
                    Hout[((size_t)p * SLOT_CAP + srow) * 32 +
                         ((c2 ^ ((srow >> 1) & 3)) << 3) + j2] = f2h(g);
                }
            } else {
                int tok = tos[srow];
                float* orow = Out + (size_t)tok * DIM + n0 + wn * 64 + fr;
#pragma unroll
                for (int ni = 0; ni < 4; ++ni)
                    atomicAdd(&orow[ni * 16], acc[mi][ni][rr]);
            }
        }
    }
}

// ---------------- Fallback 128-tile GEMM (reg-staged fp32 B; used if ws too small) ----------------
template <int PHASE>
__global__ __launch_bounds__(256) void k_gemm_fb(
    const unsigned short* __restrict__ Asrc, const float* __restrict__ Bf,
    unsigned short* __restrict__ Hout, float* __restrict__ Out,
    const int* __restrict__ ctl, const int* __restrict__ tos,
    const float* __restrict__ gos)
{
    constexpr int KD = (PHASE == 1) ? DIM : FF;
    constexpr int ND = (PHASE == 1) ? FF : DIM;
    constexpr int KT = KD / 64;

    const int tidx = blockIdx.y;
    if (tidx >= ctl[33]) return;
    const int e  = ctl[184 + tidx];
    const int m0 = ctl[320 + tidx];
    const int n0 = blockIdx.x * 128;

    __shared__ __align__(16) unsigned short Al[128 * 64];
    __shared__ __align__(16) unsigned short Bl[128 * 64];
    char* Alc = (char*)Al;
    char* Blc = (char*)Bl;

    const int t = threadIdx.x, lane = t & 63, wv = t >> 6;
    const int wm = wv >> 1, wn = wv & 1;

    const unsigned short* asrc[4];
    if (PHASE == 1) {
        const int swz = ((lane & 7) ^ (lane >> 3)) * 8;
#pragma unroll
        for (int i = 0; i < 4; ++i) {
            int row = i * 32 + wv * 8 + (lane >> 3);
            asrc[i] = Asrc + (size_t)tos[m0 + row] * KD + swz;
        }
    }
    const int lin = wv * 512 + lane * 8;

    f32x4 acc[4][4];
#pragma unroll
    for (int a = 0; a < 4; ++a)
#pragma unroll
        for (int b = 0; b < 4; ++b) acc[a][b] = f32x4{0.f, 0.f, 0.f, 0.f};

    for (int kt = 0; kt < KT; ++kt) {
        if (PHASE == 1) {
#pragma unroll
            for (int i = 0; i < 4; ++i)
                gl_lds16(asrc[i] + kt * 64, Al + i * 2048 + wv * 512);
        } else {
            const unsigned short* ab = Asrc + ((size_t)kt * SLOT_CAP + m0) * 64;
#pragma unroll
            for (int i = 0; i < 4; ++i)
                gl_lds16(ab + i * 2048 + lin, Al + i * 2048 + wv * 512);
        }
        {
            const float* Wf = Bf + (size_t)e * KD * ND;
            const int kb = (wv >> 1) * 32 + (lane >> 4) * 8;
            const int n4 = (wv & 1) * 64 + (lane & 15) * 4;
            f32x4 rr[8];
#pragma unroll
            for (int r2 = 0; r2 < 8; ++r2)
                rr[r2] = *reinterpret_cast<const f32x4*>(
                    Wf + (size_t)(kt * 64 + kb + r2) * ND + n0 + n4);
#pragma unroll
            for (int m = 0; m < 4; ++m) {
                f16x8 v;
#pragma unroll
                for (int r2 = 0; r2 < 8; ++r2) v[r2] = (_Float16)rr[r2][m];
                int nn = n4 + m;
                *reinterpret_cast<f16x8*>(Blc + nn * 128 + (((kb >> 3) ^ (nn & 7)) << 4)) = v;
            }
        }
        __syncthreads();
#pragma unroll
        for (int kc = 0; kc < 2; ++kc) {
            const int cb = kc * 4 + (lane >> 4);
            f16x8 af[4], bf[4];
#pragma unroll
            for (int mi = 0; mi < 4; ++mi) {
                int row = wm * 64 + mi * 16 + (lane & 15);
                af[mi] = *reinterpret_cast<const f16x8*>(Alc + row * 128 + ((cb ^ (row & 7)) << 4));
            }
#pragma unroll
            for (int ni = 0; ni < 4; ++ni) {
                int col = wn * 64 + ni * 16 + (lane & 15);
                bf[ni] = *reinterpret_cast<const f16x8*>(Blc + col * 128 + ((cb ^ (col & 7)) << 4));
            }
#pragma unroll
            for (int mi = 0; mi < 4; ++mi)
#pragma unroll
                for (int ni = 0; ni < 4; ++ni)
                    acc[mi][ni] = __builtin_amdgcn_mfma_f32_16x16x32_f16(
                        af[mi], bf[ni], acc[mi][ni], 0, 0, 0);
        }
        __syncthreads();
    }

#pragma unroll
    for (int mi = 0; mi < 4; ++mi) {
#pragma unroll
        for (int rr = 0; rr < 4; ++rr) {
            const int srow = m0 + wm * 64 + mi * 16 + (lane >> 4) * 4 + rr;
            if (PHASE == 1) {
                const float gate = gos[srow];
#pragma unroll
                for (int ni = 0; ni < 4; ++ni) {
                    int col = n0 + wn * 64 + ni * 16 + (lane & 15);
                    float v = acc[mi][ni][rr];
                    float g = gate * 0.5f * v * (1.f + erff(v * 0.70710678118654752f));
                    int kl = col & 63;
                    Hout[((size_t)(col >> 6) * SLOT_CAP + srow) * 64 +
                         (((kl >> 3) ^ (srow & 7)) << 3) + (kl & 7)] = f2h(g);
                }
            } else {
                int tok = tos[srow];
                float* orow = Out + (size_t)tok * DIM + n0 + wn * 64 + (lane & 15);
#pragma unroll
                for (int ni = 0; ni < 4; ++ni)
                    atomicAdd(&orow[ni * 16], acc[mi][ni][rr]);
            }
        }
    }
}

// ---------------- launch ----------------
extern "C" void kernel_launch(void* const* d_in, const int* in_sizes, int n_in,
                              void* d_out, int out_size, void* d_ws, size_t ws_size,
                              hipStream_t stream) {
    (void)in_sizes; (void)n_in;
    const float* x  = (const float*)d_in[0];
    const float* Wr = (const float*)d_in[1];
    const float* W1 = (const float*)d_in[2];
    const float* W2 = (const float*)d_in[3];
    float* out = (float*)d_out;
    char* ws = (char*)d_ws;

    // ws layout (bytes):
    //   0          ctl (4 KB)
    //   4096       tok2e (64 KB)
    //   69632      tok2w (64 KB)
    //   135168     tos (18432*4)
    //   208896     gos (18432*4)
    //   282624     xh fp16 (16 MB)            -> 17,059,840
    //   17059840   H2 fp16 plane-fmt (151 MB) -> 168,054,784
    //   168054784  Wt fp16 (64 MB, reused)    -> 235,163,648
    const size_t NEED_FB   = 168054784ULL;
    const size_t NEED_FULL = 235163648ULL;
    if (ws_size < NEED_FB) return;
    const bool big = ws_size >= NEED_FULL;

    int*            ctl = (int*)(ws + 0);
    int*            t2e = (int*)(ws + 4096);
    float*          t2w = (float*)(ws + 69632);
    int*            tos = (int*)(ws + 135168);
    float*          gos = (float*)(ws + 208896);
    unsigned short* xh  = (unsigned short*)(ws + 282624);
    unsigned short* H2  = (unsigned short*)(ws + 17059840);
    unsigned short* Wt  = (unsigned short*)(ws + 168054784);

    hipMemsetAsync(ctl, 0, 64, stream);
    hipMemsetAsync(d_out, 0, (size_t)out_size * 4, stream);

    k_router <<<dim3(N_TOK / 4), dim3(256), 0, stream>>>(x, Wr, xh, t2e, t2w);
    k_count  <<<dim3(N_TOK / 256), dim3(256), 0, stream>>>(t2e, ctl);
    k_setup  <<<dim3(1), dim3(256), 0, stream>>>(ctl, tos, gos);
    k_scatter<<<dim3(N_TOK / 256), dim3(256), 0, stream>>>(t2e, t2w, ctl, tos, gos);

    if (big) {
        k_wcvt<<<dim3(64, 16, 8), dim3(256), 0, stream>>>(W1, Wt, DIM, FF);
        k_gp32<1><<<dim3(FF / 128, MAXT128), dim3(256), 0, stream>>>(
            xh, Wt, H2, nullptr, ctl, tos, gos);
        k_wcvt<<<dim3(16, 64, 8), dim3(256), 0, stream>>>(W2, Wt, FF, DIM);
        k_gp32<2><<<dim3(DIM / 128, MAXT128), dim3(256), 0, stream>>>(
            H2, Wt, nullptr, out, ctl, tos, gos);
    } else {
        k_gemm_fb<1><<<dim3(FF / 128, MAXT128), dim3(256), 0, stream>>>(
            xh, W1, H2, nullptr, ctl, tos, gos);
        k_gemm_fb<2><<<dim3(DIM / 128, MAXT128), dim3(256), 0, stream>>>(
            H2, W2, nullptr, out, ctl, tos, gos);
    }
}

// Round 9
// 513.510 us; speedup vs baseline: 1.8108x; 1.0473x over previous
//
#include <hip/hip_runtime.h>
#include <math.h>

#define N_TOK 8192
#define DIM 1024
#define FF 4096
#define NE 8
#define SLOT_CAP (N_TOK*2 + NE*256)   // 18432
#define MAXT128 136

typedef float f32x4 __attribute__((ext_vector_type(4)));
typedef _Float16 f16x8 __attribute__((ext_vector_type(8)));
typedef unsigned int u32x4 __attribute__((ext_vector_type(4)));

__device__ __forceinline__ unsigned short f2h(float f) {
    _Float16 h = (_Float16)f;
    return __builtin_bit_cast(unsigned short, h);
}

// gelu(exact-erf form) via tanh identity; max |err| ~2e-4, << fp16 rounding
__device__ __forceinline__ float fast_gelu(float v) {
    float u = v * v;
    float p = __builtin_fmaf(0.044715f, u, 1.0f);
    float y2 = v * p * 1.5957691216057308f;            // 2*sqrt(2/pi)*(v + c v^3)
    float ex = __expf(y2);
    float r = __builtin_amdgcn_rcpf(ex + 1.0f);        // 1/(e^{2y}+1)
    return v - v * r;                                  // v*(1+tanh(y))/2
}

__device__ __forceinline__ void gl_lds16(const void* g, void* l) {
    __builtin_amdgcn_global_load_lds(
        (const __attribute__((address_space(1))) void*)g,
        (__attribute__((address_space(3))) void*)l, 16, 0, 0);
}

__device__ __forceinline__ void vw8() { asm volatile("s_waitcnt vmcnt(8)"   ::: "memory"); __builtin_amdgcn_sched_barrier(0); }
__device__ __forceinline__ void vw4() { asm volatile("s_waitcnt vmcnt(4)"   ::: "memory"); __builtin_amdgcn_sched_barrier(0); }
__device__ __forceinline__ void vw0() { asm volatile("s_waitcnt vmcnt(0)"   ::: "memory"); __builtin_amdgcn_sched_barrier(0); }
__device__ __forceinline__ void lw0() { asm volatile("s_waitcnt lgkmcnt(0)" ::: "memory"); __builtin_amdgcn_sched_barrier(0); }
#define BAR __builtin_amdgcn_s_barrier()

// ---------------- Router: fp32 logits, top-2, softmax weights, x->fp16 ----------------
__global__ __launch_bounds__(256) void k_router(
    const float* __restrict__ x, const float* __restrict__ Wr,
    unsigned short* __restrict__ xh,
    int* __restrict__ tok2e, float* __restrict__ tok2w)
{
    __shared__ float wr[NE * DIM];
    const int t = threadIdx.x;
#pragma unroll
    for (int i = 0; i < (NE * DIM) / 256; ++i) wr[i * 256 + t] = Wr[i * 256 + t];
    __syncthreads();

    const int lane = t & 63;
    const int n = blockIdx.x * 4 + (t >> 6);
    const float* xr = x + (size_t)n * DIM;
    unsigned short* xhr = xh + (size_t)n * DIM;

    float acc[NE];
#pragma unroll
    for (int e = 0; e < NE; ++e) acc[e] = 0.f;
#pragma unroll
    for (int j = 0; j < DIM / 64; ++j) {
        int d = j * 64 + lane;
        float v = xr[d];
        xhr[d] = f2h(v);
#pragma unroll
        for (int e = 0; e < NE; ++e) acc[e] += v * wr[e * DIM + d];
    }
#pragma unroll
    for (int off = 32; off >= 1; off >>= 1) {
#pragma unroll
        for (int e = 0; e < NE; ++e) acc[e] += __shfl_xor(acc[e], off);
    }
    if (lane == 0) {
        int e0 = 0; float v0 = acc[0];
#pragma unroll
        for (int e = 1; e < NE; ++e) if (acc[e] > v0) { v0 = acc[e]; e0 = e; }
        int e1 = -1; float v1 = -1e30f;
#pragma unroll
        for (int e = 0; e < NE; ++e) if (e != e0 && acc[e] > v1) { v1 = acc[e]; e1 = e; }
        float tt = expf(v1 - v0);
        tok2e[2 * n] = e0; tok2e[2 * n + 1] = e1;
        tok2w[2 * n] = 1.f / (1.f + tt); tok2w[2 * n + 1] = tt / (1.f + tt);
    }
}

// ---------------- Count: LDS histogram, 8 global atomics per block ----------------
__global__ __launch_bounds__(256) void k_count(
    const int* __restrict__ tok2e, int* __restrict__ ctl)
{
    __shared__ int h[NE];
    const int t = threadIdx.x;
    if (t < NE) h[t] = 0;
    __syncthreads();
    const int n = blockIdx.x * 256 + t;
    atomicAdd(&h[tok2e[2 * n]], 1);
    atomicAdd(&h[tok2e[2 * n + 1]], 1);
    __syncthreads();
    if (t < NE) atomicAdd(&ctl[t], h[t]);
}

// ---------------- Setup: 256-padded offsets, tile maps, parallel pad fill ----------------
__global__ __launch_bounds__(256) void k_setup(
    int* __restrict__ ctl, int* __restrict__ tos, float* __restrict__ gos)
{
    __shared__ int sh[NE * 2];
    const int t = threadIdx.x;
    if (t == 0) {
        int run = 0, T = 0, T128 = 0;
        for (int e = 0; e < NE; ++e) {
            ctl[16 + e] = run;
            int c = ctl[e];
            sh[e] = run; sh[NE + e] = c;
            int mt = (c + 255) >> 8;
            for (int j = 0; j < mt; ++j) { ctl[40 + T] = e; ctl[112 + T] = run + j * 256; ++T; }
            int mt128 = (c + 127) >> 7;
            for (int j = 0; j < mt128; ++j) { ctl[184 + T128] = e; ctl[320 + T128] = run + j * 128; ++T128; }
            run += mt * 256;
        }
        ctl[16 + NE] = run;
        ctl[32] = T; ctl[33] = T128;
    }
    __syncthreads();
    for (int e = 0; e < NE; ++e) {
        int off = sh[e], c = sh[NE + e];
        int pad = ((c + 255) >> 8) << 8;
        for (int s = c + t; s < pad; s += 256) { tos[off + s] = 0; gos[off + s] = 0.f; }
    }
}

// ---------------- Scatter: LDS histogram + block-level cursor reservation ----------------
__global__ __launch_bounds__(256) void k_scatter(
    const int* __restrict__ tok2e, const float* __restrict__ tok2w,
    int* __restrict__ ctl, int* __restrict__ tos, float* __restrict__ gos)
{
    __shared__ int h[NE], base[NE];
    const int t = threadIdx.x;
    if (t < NE) h[t] = 0;
    __syncthreads();
    const int n = blockIdx.x * 256 + t;
    const int e0 = tok2e[2 * n], e1 = tok2e[2 * n + 1];
    const int p0 = atomicAdd(&h[e0], 1);
    const int p1 = atomicAdd(&h[e1], 1);
    __syncthreads();
    if (t < NE) base[t] = ctl[16 + t] + atomicAdd(&ctl[8 + t], h[t]);
    __syncthreads();
    const int s0 = base[e0] + p0, s1 = base[e1] + p1;
    tos[s0] = n; gos[s0] = tok2w[2 * n];
    tos[s1] = n; gos[s1] = tok2w[2 * n + 1];
}

// ---------------- W convert: fp32 [E][KD][ND] -> fp16 planes [e][ktt(32k)][n][32] chunk-swizzled ----------------
__global__ __launch_bounds__(256) void k_wcvt(
    const float* __restrict__ W, unsigned short* __restrict__ Wt, int KD, int ND)
{
    __shared__ unsigned short Lt[64][72];
    const int t = threadIdx.x;
    const int e = blockIdx.z, kt = blockIdx.y, n0 = blockIdx.x * 64;
    const int KT = KD >> 6;
    const float* src = W + (size_t)e * KD * ND + (size_t)(kt * 64) * ND + n0;
#pragma unroll
    for (int i = 0; i < 4; ++i) {
        int kl = (t >> 4) + i * 16;
        f32x4 v = *reinterpret_cast<const f32x4*>(src + (size_t)kl * ND + (t & 15) * 4);
        int h = kl >> 5, c = (kl >> 3) & 3, j = kl & 7;
#pragma unroll
        for (int m = 0; m < 4; ++m) {
            int nl = (t & 15) * 4 + m;
            Lt[nl][h * 32 + ((c ^ ((nl >> 1) & 3)) << 3) + j] = f2h(v[m]);
        }
    }
    __syncthreads();
    const int nl = t >> 2, qq = t & 3;
#pragma unroll
    for (int h = 0; h < 2; ++h) {
        unsigned short* dst = Wt + ((size_t)(e * KT + kt) * 2 + h) * ((size_t)ND * 32)
                            + (size_t)(n0 + nl) * 32 + qq * 8;
        *reinterpret_cast<u32x4*>(dst) = *reinterpret_cast<const u32x4*>(&Lt[nl][h * 32 + qq * 8]);
    }
}

// ---- fragment / mfma macros (static register sets X/Y) ----
#define LDF(SET, BOFF) do {                                                   \
    const char* ba_ = lds + (BOFF) + A0;                                      \
    const char* bb_ = lds + (BOFF) + 8192 + B0;                               \
    _Pragma("unroll")                                                         \
    for (int i_ = 0; i_ < 4; ++i_) af##SET[i_] = *(const f16x8*)(ba_ + i_ * 1024); \
    _Pragma("unroll")                                                         \
    for (int i_ = 0; i_ < 4; ++i_) bf##SET[i_] = *(const f16x8*)(bb_ + i_ * 1024); \
} while (0)

#define MMS(SET) do {                                                         \
    __builtin_amdgcn_s_setprio(1);                                            \
    _Pragma("unroll")                                                         \
    for (int mi_ = 0; mi_ < 4; ++mi_)                                         \
        _Pragma("unroll")                                                     \
        for (int ni_ = 0; ni_ < 4; ++ni_)                                     \
            acc[mi_][ni_] = __builtin_amdgcn_mfma_f32_16x16x32_f16(           \
                af##SET[mi_], bf##SET[ni_], acc[mi_][ni_], 0, 0, 0);          \
    __builtin_amdgcn_s_setprio(0);                                            \
} while (0)

#define ROT3 do { int tmp_ = bs; bs = br; br = bt; bt = tmp_; } while (0)

// ---------------- 128x128 BK=32, 3-buf LDS, reg-double-buffered frags, 1 barrier/tile ----------------
// iter i: BAR; STAGE(i+3 -> buf[i%3]); issue LDF(i+1); MFMA(i) overlaps; lgkm0; vmcnt4 (tile i+2 landed)
template <int PHASE>
__global__ __launch_bounds__(256) void k_gp3(
    const unsigned short* __restrict__ Asrc, const unsigned short* __restrict__ Bh,
    unsigned short* __restrict__ Hout, float* __restrict__ Out,
    const int* __restrict__ ctl, const int* __restrict__ tos,
    const float* __restrict__ gos)
{
    constexpr int KD = (PHASE == 1) ? DIM : FF;
    constexpr int ND = (PHASE == 1) ? FF : DIM;
    constexpr int KT = KD / 32;
    constexpr int NX = ND / 128;

    // bijective XCD remap: each XCD sweeps N-tiles of its M-tiles
    const int lin = blockIdx.y * NX + blockIdx.x;
    const int xcd = lin & 7, chunk = lin >> 3;
    const int xp = chunk & (NX - 1);
    const int yp = (chunk / NX) * 8 + xcd;
    if (yp >= ctl[33]) return;
    const int e  = ctl[184 + yp];
    const int m0 = ctl[320 + yp];
    const int n0 = xp * 128;

    __shared__ __align__(1024) char lds[3 * 16384];   // 3 bufs x (A 8K + B 8K)

    const int t = threadIdx.x, l = t & 63, w = t >> 6;
    const int wm = w >> 1, wn = w & 1;                 // 2x2 waves, 64x64 per wave
    const int fr = l & 15, hi = l >> 4;

    // staging sources
    const char* pa0; const char* pa1; const char* pb;
    if constexpr (PHASE == 1) {
        const int swz = ((l & 3) ^ ((l >> 3) & 3)) << 4;   // pre-swizzled source chunk
        pa0 = (const char*)Asrc + (size_t)tos[m0 + w * 32 + (l >> 2)]      * 2048 + swz;
        pa1 = (const char*)Asrc + (size_t)tos[m0 + w * 32 + 16 + (l >> 2)] * 2048 + swz;
    } else {
        pa0 = (const char*)Asrc + (size_t)m0 * 64 + w * 2048 + l * 16;   // H2 pre-swizzled
        pa1 = nullptr;
    }
    pb = (const char*)Bh + (size_t)e * KD * ND * 2 + (size_t)n0 * 64 + w * 2048 + l * 16;

    auto STAGE = [&](int ktt, int boff) {
        char* da = lds + boff + w * 2048;
        char* db = lds + boff + 8192 + w * 2048;
        if constexpr (PHASE == 1) {
            gl_lds16(pa0 + ktt * 64, da);
            gl_lds16(pa1 + ktt * 64, da + 1024);
        } else {
            const char* s = pa0 + (size_t)ktt * (SLOT_CAP * 64);
            gl_lds16(s, da);
            gl_lds16(s + 1024, da + 1024);
        }
        const char* sb = pb + (size_t)ktt * (ND * 64);
        gl_lds16(sb, db);
        gl_lds16(sb + 1024, db + 1024);
    };

    // ds_read bases; swizzle key (row>>1)&3 (measured conflict-free)
    const int key = (fr >> 1) & 3;
    const int A0 = (wm * 64 + fr) * 64 + ((hi ^ key) << 4);
    const int B0 = (wn * 64 + fr) * 64 + ((hi ^ key) << 4);

    f16x8 afX[4], bfX[4], afY[4], bfY[4];
    f32x4 acc[4][4];
#pragma unroll
    for (int a = 0; a < 4; ++a)
#pragma unroll
        for (int b = 0; b < 4; ++b) acc[a][b] = f32x4{0.f, 0.f, 0.f, 0.f};

    // ---- prologue: stage tiles 0,1,2; frags(0)->X; tile1 confirmed ----
    STAGE(0, 0); STAGE(1, 16384); STAGE(2, 32768);
    vw8();                       // tile 0 landed ({1,2} in flight)
    BAR;
    LDF(X, 0);                   // frags of tile 0
    lw0();                       // mine read
    vw4();                       // tile 1 landed ({2} in flight)

    // ---- iter 0 (even) ----
    BAR;
    STAGE(3, 0);                 // buf0 free (all waves past lw0 via BAR)
    LDF(Y, 16384);               // issue frags(1); no wait yet
    MMS(X);                      // MFMA tile 0 overlaps DMA + ds_reads
    lw0();                       // frags(1) ready
    vw4();                       // tile 2 landed ({3} in flight)

    int bs = 16384, br = 32768, bt = 0;
    // ---- steady pairs: i = 1,3,...,KT-5 (full iters through i=KT-4) ----
    for (int i = 1; i < KT - 4; i += 2) {
        BAR; STAGE(i + 3, bs); LDF(X, br); MMS(Y); lw0(); vw4();
        ROT3;
        BAR; STAGE(i + 4, bs); LDF(Y, br); MMS(X); lw0(); vw4();
        ROT3;
    }
    // ---- drain: i = KT-3 (odd), KT-2 (even), KT-1 (odd) ----
    BAR; LDF(X, br); MMS(Y); lw0(); vw0();
    ROT3;
    BAR; LDF(Y, br); MMS(X); lw0();
    MMS(Y);

    // ---- epilogue ----
#pragma unroll
    for (int mi = 0; mi < 4; ++mi) {
#pragma unroll
        for (int rr = 0; rr < 4; ++rr) {
            const int srow = m0 + wm * 64 + mi * 16 + hi * 4 + rr;
            if constexpr (PHASE == 1) {
                const float gate = gos[srow];
#pragma unroll
                for (int ni = 0; ni < 4; ++ni) {
                    int col = n0 + wn * 64 + ni * 16 + fr;
                    float g = gate * fast_gelu(acc[mi][ni][rr]);
                    int p = col >> 5, c2 = (col >> 3) & 3, j2 = col & 7;
                    Hout[((size_t)p * SLOT_CAP + srow) * 32 +
                         ((c2 ^ ((srow >> 1) & 3)) << 3) + j2] = f2h(g);
                }
            } else {
                int tok = tos[srow];
                float* orow = Out + (size_t)tok * DIM + n0 + wn * 64 + fr;
#pragma unroll
                for (int ni = 0; ni < 4; ++ni)
                    atomicAdd(&orow[ni * 16], acc[mi][ni][rr]);
            }
        }
    }
}

// ---------------- Fallback 128-tile GEMM (reg-staged fp32 B; used if ws too small) ----------------
template <int PHASE>
__global__ __launch_bounds__(256) void k_gemm_fb(
    const unsigned short* __restrict__ Asrc, const float* __restrict__ Bf,
    unsigned short* __restrict__ Hout, float* __restrict__ Out,
    const int* __restrict__ ctl, const int* __restrict__ tos,
    const float* __restrict__ gos)
{
    constexpr int KD = (PHASE == 1) ? DIM : FF;
    constexpr int ND = (PHASE == 1) ? FF : DIM;
    constexpr int KT = KD / 64;

    const int tidx = blockIdx.y;
    if (tidx >= ctl[33]) return;
    const int e  = ctl[184 + tidx];
    const int m0 = ctl[320 + tidx];
    const int n0 = blockIdx.x * 128;

    __shared__ __align__(16) unsigned short Al[128 * 64];
    __shared__ __align__(16) unsigned short Bl[128 * 64];
    char* Alc = (char*)Al;
    char* Blc = (char*)Bl;

    const int t = threadIdx.x, lane = t & 63, wv = t >> 6;
    const int wm = wv >> 1, wn = wv & 1;

    const unsigned short* asrc[4];
    if (PHASE == 1) {
        const int swz = ((lane & 7) ^ (lane >> 3)) * 8;
#pragma unroll
        for (int i = 0; i < 4; ++i) {
            int row = i * 32 + wv * 8 + (lane >> 3);
            asrc[i] = Asrc + (size_t)tos[m0 + row] * KD + swz;
        }
    }
    const int lin = wv * 512 + lane * 8;

    f32x4 acc[4][4];
#pragma unroll
    for (int a = 0; a < 4; ++a)
#pragma unroll
        for (int b = 0; b < 4; ++b) acc[a][b] = f32x4{0.f, 0.f, 0.f, 0.f};

    for (int kt = 0; kt < KT; ++kt) {
        if (PHASE == 1) {
#pragma unroll
            for (int i = 0; i < 4; ++i)
                gl_lds16(asrc[i] + kt * 64, Al + i * 2048 + wv * 512);
        } else {
            const unsigned short* ab = Asrc + ((size_t)kt * SLOT_CAP + m0) * 64;
#pragma unroll
            for (int i = 0; i < 4; ++i)
                gl_lds16(ab + i * 2048 + lin, Al + i * 2048 + wv * 512);
        }
        {
            const float* Wf = Bf + (size_t)e * KD * ND;
            const int kb = (wv >> 1) * 32 + (lane >> 4) * 8;
            const int n4 = (wv & 1) * 64 + (lane & 15) * 4;
            f32x4 rr[8];
#pragma unroll
            for (int r2 = 0; r2 < 8; ++r2)
                rr[r2] = *reinterpret_cast<const f32x4*>(
                    Wf + (size_t)(kt * 64 + kb + r2) * ND + n0 + n4);
#pragma unroll
            for (int m = 0; m < 4; ++m) {
                f16x8 v;
#pragma unroll
                for (int r2 = 0; r2 < 8; ++r2) v[r2] = (_Float16)rr[r2][m];
                int nn = n4 + m;
                *reinterpret_cast<f16x8*>(Blc + nn * 128 + (((kb >> 3) ^ (nn & 7)) << 4)) = v;
            }
        }
        __syncthreads();
#pragma unroll
        for (int kc = 0; kc < 2; ++kc) {
            const int cb = kc * 4 + (lane >> 4);
            f16x8 af[4], bf[4];
#pragma unroll
            for (int mi = 0; mi < 4; ++mi) {
                int row = wm * 64 + mi * 16 + (lane & 15);
                af[mi] = *reinterpret_cast<const f16x8*>(Alc + row * 128 + ((cb ^ (row & 7)) << 4));
            }
#pragma unroll
            for (int ni = 0; ni < 4; ++ni) {
                int col = wn * 64 + ni * 16 + (lane & 15);
                bf[ni] = *reinterpret_cast<const f16x8*>(Blc + col * 128 + ((cb ^ (col & 7)) << 4));
            }
#pragma unroll
            for (int mi = 0; mi < 4; ++mi)
#pragma unroll
                for (int ni = 0; ni < 4; ++ni)
                    acc[mi][ni] = __builtin_amdgcn_mfma_f32_16x16x32_f16(
                        af[mi], bf[ni], acc[mi][ni], 0, 0, 0);
        }
        __syncthreads();
    }

#pragma unroll
    for (int mi = 0; mi < 4; ++mi) {
#pragma unroll
        for (int rr = 0; rr < 4; ++rr) {
            const int srow = m0 + wm * 64 + mi * 16 + (lane >> 4) * 4 + rr;
            if (PHASE == 1) {
                const float gate = gos[srow];
#pragma unroll
                for (int ni = 0; ni < 4; ++ni) {
                    int col = n0 + wn * 64 + ni * 16 + (lane & 15);
                    float g = gate * fast_gelu(acc[mi][ni][rr]);
                    int kl = col & 63;
                    Hout[((size_t)(col >> 6) * SLOT_CAP + srow) * 64 +
                         (((kl >> 3) ^ (srow & 7)) << 3) + (kl & 7)] = f2h(g);
                }
            } else {
                int tok = tos[srow];
                float* orow = Out + (size_t)tok * DIM + n0 + wn * 64 + (lane & 15);
#pragma unroll
                for (int ni = 0; ni < 4; ++ni)
                    atomicAdd(&orow[ni * 16], acc[mi][ni][rr]);
            }
        }
    }
}

// ---------------- launch ----------------
extern "C" void kernel_launch(void* const* d_in, const int* in_sizes, int n_in,
                              void* d_out, int out_size, void* d_ws, size_t ws_size,
                              hipStream_t stream) {
    (void)in_sizes; (void)n_in;
    const float* x  = (const float*)d_in[0];
    const float* Wr = (const float*)d_in[1];
    const float* W1 = (const float*)d_in[2];
    const float* W2 = (const float*)d_in[3];
    float* out = (float*)d_out;
    char* ws = (char*)d_ws;

    // ws layout (bytes):
    //   0          ctl (4 KB)
    //   4096       tok2e (64 KB)
    //   69632      tok2w (64 KB)
    //   135168     tos (18432*4)
    //   208896     gos (18432*4)
    //   282624     xh fp16 (16 MB)            -> 17,059,840
    //   17059840   H2 fp16 plane-fmt (151 MB) -> 168,054,784
    //   168054784  Wt fp16 (64 MB, reused)    -> 235,163,648
    const size_t NEED_FB   = 168054784ULL;
    const size_t NEED_FULL = 235163648ULL;
    if (ws_size < NEED_FB) return;
    const bool big = ws_size >= NEED_FULL;

    int*            ctl = (int*)(ws + 0);
    int*            t2e = (int*)(ws + 4096);
    float*          t2w = (float*)(ws + 69632);
    int*            tos = (int*)(ws + 135168);
    float*          gos = (float*)(ws + 208896);
    unsigned short* xh  = (unsigned short*)(ws + 282624);
    unsigned short* H2  = (unsigned short*)(ws + 17059840);
    unsigned short* Wt  = (unsigned short*)(ws + 168054784);

    hipMemsetAsync(ctl, 0, 64, stream);
    hipMemsetAsync(d_out, 0, (size_t)out_size * 4, stream);

    k_router <<<dim3(N_TOK / 4), dim3(256), 0, stream>>>(x, Wr, xh, t2e, t2w);
    k_count  <<<dim3(N_TOK / 256), dim3(256), 0, stream>>>(t2e, ctl);
    k_setup  <<<dim3(1), dim3(256), 0, stream>>>(ctl, tos, gos);
    k_scatter<<<dim3(N_TOK / 256), dim3(256), 0, stream>>>(t2e, t2w, ctl, tos, gos);

    if (big) {
        k_wcvt<<<dim3(64, 16, 8), dim3(256), 0, stream>>>(W1, Wt, DIM, FF);
        k_gp3<1><<<dim3(FF / 128, MAXT128), dim3(256), 0, stream>>>(
            xh, Wt, H2, nullptr, ctl, tos, gos);
        k_wcvt<<<dim3(16, 64, 8), dim3(256), 0, stream>>>(W2, Wt, FF, DIM);
        k_gp3<2><<<dim3(DIM / 128, MAXT128), dim3(256), 0, stream>>>(
            H2, Wt, nullptr, out, ctl, tos, gos);
    } else {
        k_gemm_fb<1><<<dim3(FF / 128, MAXT128), dim3(256), 0, stream>>>(
            xh, W1, H2, nullptr, ctl, tos, gos);
        k_gemm_fb<2><<<dim3(DIM / 128, MAXT128), dim3(256), 0, stream>>>(
            H2, W2, nullptr, out, ctl, tos, gos);
    }
}